// Round 15
// baseline (429.244 us; speedup 1.0000x reference)
//
#include <hip/hip_runtime.h>
#include <hip/hip_bf16.h>

#define NR_ 40000
#define NV_ 4000
#define ERR_ 400000
#define EVR_ 150000
#define ERV_ 150000
#define ETOT_ (ERR_ + EVR_ + ERV_)
#define NTOT_ (NR_ + NR_ + NV_)
#define SCAN_ELEMS 512
#define SCAN_NB ((NTOT_ + SCAN_ELEMS - 1) / SCAN_ELEMS)   // 165
#define BN_BLKS_R ((NR_ + 63) / 64)  // 625
#define BN_BLKS_V ((NV_ + 63) / 64)  // 63
#define L1B_R ((NR_ + 31) / 32)      // 1250
#define L1B_V ((NV_ + 31) / 32)      // 125
#define L1B_TOT (2 * L1B_R + L1B_V)  // 2625
#define MFB_R ((NR_ + 63) / 64)      // 625
#define MFB_V ((NV_ + 63) / 64)      // 63
#define AGB_R ((NR_ + 3) / 4)        // 10000
#define AGB_V ((NV_ + 3) / 4)        // 1000
#define BNN_R ((NR_ + 3) / 4)
#define BNN_V ((NV_ + 3) / 4)
#define HISTB ((ETOT_ + 255) / 256)  // 2735
#define PREB (14 + 192)              // fold/misc blocks + Wt blocks (256 thr): 49152/256=192
#define NEG_ 0.2f
#define EPS_ 1e-5f

typedef __attribute__((ext_vector_type(8))) __bf16 bfrag;
typedef __attribute__((ext_vector_type(4))) float ffrag;
typedef __attribute__((ext_vector_type(4))) __bf16 bf4;
typedef __attribute__((ext_vector_type(2))) __bf16 bf2;

// ================= precompute (folds, wp2, fw, Wt-transpose) + hist, one launch =================

__global__ __launch_bounds__(256) void precompute_hist(
        const float* __restrict__ Wsrc1, const float* __restrict__ Wdst1,
        const float* __restrict__ asrc1, const float* __restrict__ adst1,
        const float* __restrict__ Wsrc2, const float* __restrict__ Wdst2,
        const float* __restrict__ asrc2, const float* __restrict__ adst2,
        const float* __restrict__ Wp, const float* __restrict__ bp,
        const float* __restrict__ Wlin, const float* __restrict__ blin,
        const int* __restrict__ ei_rr, const int* __restrict__ ei_vr, const int* __restrict__ ei_rv,
        float* __restrict__ foldR, float* __restrict__ foldV,
        float* __restrict__ wp2, float* __restrict__ cterm,
        float* __restrict__ fw, __bf16* __restrict__ Wt,
        int* __restrict__ cnt) {
    int b = blockIdx.x;
    int t = threadIdx.x;
    if (b < 12) {
        int layer = b / 6, rel = (b % 6) / 2, side = b & 1;
        int K = (layer == 0) ? 16 : 128;
        const float* W = (layer == 0) ? (side ? Wdst1 : Wsrc1) : (side ? Wdst2 : Wsrc2);
        const float* a = (layer == 0) ? (side ? adst1 : asrc1) : (side ? adst2 : asrc2);
        W += (size_t)rel * K * 128;
        a += rel * 128;
        float* dst; int P; int colbase;
        if (rel == 0 && side == 0)      { dst = foldR; P = 8; colbase = 0; }
        else if (rel == 0)              { dst = foldR; P = 8; colbase = 2; }
        else if (rel == 1 && side == 0) { dst = foldV; P = 4; colbase = 0; }
        else if (rel == 1)              { dst = foldR; P = 8; colbase = 4; }
        else if (side == 0)             { dst = foldR; P = 8; colbase = 6; }
        else                            { dst = foldV; P = 4; colbase = 2; }
        dst += (size_t)layer * 128 * P;
        if (t < K) {
            for (int h = 0; h < 2; ++h) {
                float s = 0.f;
                for (int c = 0; c < 64; ++c) s += W[t * 128 + h * 64 + c] * a[h * 64 + c];
                dst[t * P + colbase + h] = s;
            }
        }
    } else if (b == 12) {
        if (t < 48) {
            int i = t / 16, k = (t / 2) % 8, o = t & 1;
            float s = 0.f;
            for (int c = 0; c < 64; ++c) s += Wp[(i * 8 + k) * 64 + c] * Wlin[(128 + c) * 2 + o];
            wp2[t] = s;
        } else if (t < 54) {
            int i = (t - 48) / 2, o = (t - 48) & 1;
            float s = blin[o];
            for (int c = 0; c < 64; ++c) s += bp[i * 64 + c] * Wlin[(128 + c) * 2 + o];
            cterm[i * 2 + o] = s;
        }
    } else if (b == 13) {
        for (int idx = t; idx < 512; idx += 256) {
            int k = idx >> 2, c = idx & 3;
            fw[idx] = Wlin[(k + ((c >= 2) ? 192 : 0)) * 2 + (c & 1)];
        }
    } else if (b < PREB) {
        int i = (b - 14) * 256 + t;
        if (i < 3 * 128 * 128) {
            int rel = i >> 14, rem = i & 16383, n = rem >> 7, k = rem & 127;
            Wt[i] = (__bf16)Wsrc2[(size_t)rel * 16384 + k * 128 + n];
        }
    } else {
        int j = (b - PREB) * 256 + t;
        if (j < ERR_) atomicAdd(&cnt[ei_rr[ERR_ + j]], 1);
        else if (j < ERR_ + EVR_) atomicAdd(&cnt[NR_ + ei_vr[EVR_ + (j - ERR_)]], 1);
        else if (j < ETOT_) atomicAdd(&cnt[2 * NR_ + ei_rv[ERV_ + (j - ERR_ - EVR_)]], 1);
    }
}

// ================= scan (2 launches: reduce, then write-with-redundant-offset) =================

__global__ __launch_bounds__(256) void scan_reduce(const int* __restrict__ cnt, int* __restrict__ bsum) {
    __shared__ int buf[256];
    int t = threadIdx.x;
    int i0 = blockIdx.x * SCAN_ELEMS + t * 2;
    int s = 0;
    if (i0 + 1 < NTOT_) { int2 v = *(const int2*)&cnt[i0]; s = v.x + v.y; }
    else if (i0 < NTOT_) s = cnt[i0];
    buf[t] = s;
    __syncthreads();
    for (int off = 128; off; off >>= 1) {
        if (t < off) buf[t] += buf[t + off];
        __syncthreads();
    }
    if (t == 0) bsum[blockIdx.x] = buf[0];
}

// each block redundantly computes its global offset = sum of preceding bsums
__global__ __launch_bounds__(256) void scan_write(const int* __restrict__ cnt,
                                                  const int* __restrict__ bsum,
                                                  int* __restrict__ row, int* __restrict__ cur) {
    __shared__ int rbuf[256];
    __shared__ int buf[256];
    int t = threadIdx.x;
    int sb = (t < SCAN_NB && t < (int)blockIdx.x) ? bsum[t] : 0;
    rbuf[t] = sb;
    __syncthreads();
    for (int off = 128; off; off >>= 1) {
        if (t < off) rbuf[t] += rbuf[t + off];
        __syncthreads();
    }
    int boff = rbuf[0];

    int i0 = blockIdx.x * SCAN_ELEMS + t * 2;
    int vx = 0, vy = 0;
    if (i0 + 1 < NTOT_) { int2 v = *(const int2*)&cnt[i0]; vx = v.x; vy = v.y; }
    else if (i0 < NTOT_) vx = cnt[i0];
    int s = vx + vy;
    buf[t] = s;
    __syncthreads();
    for (int off = 1; off < 256; off <<= 1) {
        int v = (t >= off) ? buf[t - off] : 0;
        __syncthreads();
        buf[t] += v;
        __syncthreads();
    }
    int ex = buf[t] - s + boff;
    if (i0 + 1 < NTOT_) {
        *(int2*)&row[i0] = make_int2(ex, ex + vx);
        *(int2*)&cur[i0] = make_int2(ex, ex + vx);
    } else if (i0 < NTOT_) {
        row[i0] = ex;
        cur[i0] = ex;
    }
    if (blockIdx.x == 0 && t == 0) row[NTOT_] = ETOT_;
}

// ================= scatter + layer-1 GEMM (merged, block-range) =================

__global__ __launch_bounds__(256) void scatter_gemm_l1(
        const int* __restrict__ ei_rr, const int* __restrict__ ei_vr, const int* __restrict__ ei_rv,
        int* __restrict__ cur, int* __restrict__ cs,
        const float* __restrict__ x_req, const float* __restrict__ x_veh,
        const float* __restrict__ W,
        const float* __restrict__ fR, const float* __restrict__ fV,
        __bf16* __restrict__ hs_a, __bf16* __restrict__ hs_b, __bf16* __restrict__ hs_c,
        float* __restrict__ scR, float* __restrict__ scV) {
    __shared__ float xs[32][20];
    __shared__ float ws[16][128];
    __shared__ float fs[128];
    int b = blockIdx.x;
    int t = threadIdx.x;
    if (b >= L1B_TOT) {
        // ---- scatter part ----
        int j = (b - L1B_TOT) * 256 + t;
        int s, nidx;
        if (j < ERR_)             { s = ei_rr[j]; nidx = ei_rr[ERR_ + j]; }
        else if (j < ERR_ + EVR_) { int jj = j - ERR_; s = ei_vr[jj]; nidx = NR_ + ei_vr[EVR_ + jj]; }
        else if (j < ETOT_)       { int jj = j - ERR_ - EVR_; s = ei_rv[jj]; nidx = 2 * NR_ + ei_rv[ERV_ + jj]; }
        else return;
        int p = atomicAdd(&cur[nidx], 1);
        cs[p] = s;
        return;
    }
    // ---- gemm_l1 part ----
    const float* x; const float* Wr; const float* fold; __bf16* hs; float* sc; int N, P, row0;
    if (b < L1B_R)          { x = x_req; Wr = W + 0 * 2048; fold = fR; hs = hs_a; sc = scR; N = NR_; P = 8; row0 = b * 32; }
    else if (b < 2 * L1B_R) { x = x_req; Wr = W + 2 * 2048; fold = nullptr; hs = hs_c; sc = nullptr; N = NR_; P = 0; row0 = (b - L1B_R) * 32; }
    else                    { x = x_veh; Wr = W + 1 * 2048; fold = fV; hs = hs_b; sc = scV; N = NV_; P = 4; row0 = (b - 2 * L1B_R) * 32; }

    for (int v = t; v < 32 * 4; v += 256) {
        int r = v >> 2, kk = (v & 3) * 4;
        int rr = row0 + r;
        float4 val = make_float4(0.f, 0.f, 0.f, 0.f);
        if (rr < N) val = *(const float4*)&x[(size_t)rr * 16 + kk];
        *(float4*)&xs[r][kk] = val;
    }
    for (int v = t; v < 512; v += 256) ((float4*)&ws[0][0])[v] = ((const float4*)Wr)[v];
    if (P > 0)
        for (int v = t; v < 16 * P; v += 256) fs[v] = fold[v];
    __syncthreads();

    int cg4 = (t & 31) * 4;
    int rg4 = (t >> 5) * 4;
    float acc[4][4] = {{0.f}};
#pragma unroll
    for (int k = 0; k < 16; k += 4) {
        float4 xv[4];
#pragma unroll
        for (int i = 0; i < 4; ++i) xv[i] = *(const float4*)&xs[rg4 + i][k];
        float4 w0 = *(const float4*)&ws[k + 0][cg4];
        float4 w1 = *(const float4*)&ws[k + 1][cg4];
        float4 w2 = *(const float4*)&ws[k + 2][cg4];
        float4 w3 = *(const float4*)&ws[k + 3][cg4];
#pragma unroll
        for (int i = 0; i < 4; ++i) {
            acc[i][0] += xv[i].x * w0.x + xv[i].y * w1.x + xv[i].z * w2.x + xv[i].w * w3.x;
            acc[i][1] += xv[i].x * w0.y + xv[i].y * w1.y + xv[i].z * w2.y + xv[i].w * w3.y;
            acc[i][2] += xv[i].x * w0.z + xv[i].y * w1.z + xv[i].z * w2.z + xv[i].w * w3.z;
            acc[i][3] += xv[i].x * w0.w + xv[i].y * w1.w + xv[i].z * w2.w + xv[i].w * w3.w;
        }
    }
#pragma unroll
    for (int i = 0; i < 4; ++i) {
        int rr = row0 + rg4 + i;
        if (rr < N) {
            bf4 o;
            o[0] = (__bf16)acc[i][0]; o[1] = (__bf16)acc[i][1];
            o[2] = (__bf16)acc[i][2]; o[3] = (__bf16)acc[i][3];
            *(bf4*)&hs[(size_t)rr * 128 + cg4] = o;
        }
    }
    if (P > 0 && t < 32 * P) {
        int srow = t / P, scol = t % P;
        if (row0 + srow < N) {
            float s = 0.f;
            for (int k = 0; k < 16; ++k) s += xs[srow][k] * fs[k * P + scol];
            sc[(size_t)(row0 + srow) * P + scol] = s;
        }
    }
}

// ===== layer-2: all 3 projections via bf16 MFMA =====

__global__ __launch_bounds__(256) void gemm_mfma_all(const __bf16* __restrict__ xrb,
                                                     const __bf16* __restrict__ xvb,
                                                     const __bf16* __restrict__ Wt,
                                                     __bf16* __restrict__ hs_a, __bf16* __restrict__ hs_b,
                                                     __bf16* __restrict__ hs_c) {
    int b = blockIdx.x;
    const __bf16* x; const __bf16* W; __bf16* hs; int N, blk;
    if (b < MFB_R)          { x = xrb; W = Wt + 0 * 16384; hs = hs_a; N = NR_; blk = b; }
    else if (b < 2 * MFB_R) { x = xrb; W = Wt + 2 * 16384; hs = hs_c; N = NR_; blk = b - MFB_R; }
    else                    { x = xvb; W = Wt + 1 * 16384; hs = hs_b; N = NV_; blk = b - 2 * MFB_R; }
    int wave = threadIdx.x >> 6;
    int lane = threadIdx.x & 63;
    int m = lane & 15;
    int quad = lane >> 4;
    int row0 = blk * 64 + wave * 16;
    int arow = row0 + m;
    int rs = (arow < N) ? arow : (N - 1);
    const __bf16* xp = x + (size_t)rs * 128 + quad * 8;
    bfrag A0 = *(const bfrag*)(xp);
    bfrag A1 = *(const bfrag*)(xp + 32);
    bfrag A2 = *(const bfrag*)(xp + 64);
    bfrag A3 = *(const bfrag*)(xp + 96);
#pragma unroll
    for (int nt = 0; nt < 8; ++nt) {
        const __bf16* wp = W + (size_t)(nt * 16 + m) * 128 + quad * 8;
        ffrag acc = {0.f, 0.f, 0.f, 0.f};
        acc = __builtin_amdgcn_mfma_f32_16x16x32_bf16(A0, *(const bfrag*)(wp), acc, 0, 0, 0);
        acc = __builtin_amdgcn_mfma_f32_16x16x32_bf16(A1, *(const bfrag*)(wp + 32), acc, 0, 0, 0);
        acc = __builtin_amdgcn_mfma_f32_16x16x32_bf16(A2, *(const bfrag*)(wp + 64), acc, 0, 0, 0);
        acc = __builtin_amdgcn_mfma_f32_16x16x32_bf16(A3, *(const bfrag*)(wp + 96), acc, 0, 0, 0);
        int dcol = nt * 16 + m;
#pragma unroll
        for (int r = 0; r < 4; ++r) {
            int drow = row0 + quad * 4 + r;
            if (drow < N) hs[(size_t)drow * 128 + dcol] = (__bf16)acc[r];
        }
    }
}

// ================= gather-aggregate (bf16 hs), fused softmax; block 0 zeroes s4 =================

__device__ __forceinline__ void agg_rel_bf(int node, int lane,
                                           const int* __restrict__ row, const int* __restrict__ cs,
                                           const __bf16* __restrict__ hs,
                                           const float* __restrict__ Ss, int sst, int sc, float edv,
                                           float& ox, float& oy) {
    int r0 = row[node], r1 = row[node + 1];
    if (r1 <= r0) return;
    float ax = 0.f, ay = 0.f, den = 0.f;
    int j = r0;
    for (; j + 8 <= r1; j += 8) {
        int s0 = cs[j + 0], s1 = cs[j + 1], s2 = cs[j + 2], s3 = cs[j + 3];
        int s4_ = cs[j + 4], s5 = cs[j + 5], s6 = cs[j + 6], s7 = cs[j + 7];
        float p0 = Ss[s0 * sst + sc], p1 = Ss[s1 * sst + sc];
        float p2 = Ss[s2 * sst + sc], p3 = Ss[s3 * sst + sc];
        float p4 = Ss[s4_ * sst + sc], p5 = Ss[s5 * sst + sc];
        float p6 = Ss[s6 * sst + sc], p7 = Ss[s7 * sst + sc];
        bf2 v0 = *(const bf2*)&hs[(size_t)s0 * 128 + lane * 2];
        bf2 v1 = *(const bf2*)&hs[(size_t)s1 * 128 + lane * 2];
        bf2 v2 = *(const bf2*)&hs[(size_t)s2 * 128 + lane * 2];
        bf2 v3 = *(const bf2*)&hs[(size_t)s3 * 128 + lane * 2];
        bf2 v4 = *(const bf2*)&hs[(size_t)s4_ * 128 + lane * 2];
        bf2 v5 = *(const bf2*)&hs[(size_t)s5 * 128 + lane * 2];
        bf2 v6 = *(const bf2*)&hs[(size_t)s6 * 128 + lane * 2];
        bf2 v7 = *(const bf2*)&hs[(size_t)s7 * 128 + lane * 2];
        float e0 = p0 + edv; e0 = (e0 >= 0.f) ? e0 : NEG_ * e0;
        float e1 = p1 + edv; e1 = (e1 >= 0.f) ? e1 : NEG_ * e1;
        float e2 = p2 + edv; e2 = (e2 >= 0.f) ? e2 : NEG_ * e2;
        float e3 = p3 + edv; e3 = (e3 >= 0.f) ? e3 : NEG_ * e3;
        float e4 = p4 + edv; e4 = (e4 >= 0.f) ? e4 : NEG_ * e4;
        float e5 = p5 + edv; e5 = (e5 >= 0.f) ? e5 : NEG_ * e5;
        float e6 = p6 + edv; e6 = (e6 >= 0.f) ? e6 : NEG_ * e6;
        float e7 = p7 + edv; e7 = (e7 >= 0.f) ? e7 : NEG_ * e7;
        float w0 = __expf(e0), w1 = __expf(e1), w2 = __expf(e2), w3 = __expf(e3);
        float w4 = __expf(e4), w5 = __expf(e5), w6 = __expf(e6), w7 = __expf(e7);
        ax += (float)v0[0] * w0 + (float)v1[0] * w1 + (float)v2[0] * w2 + (float)v3[0] * w3
            + (float)v4[0] * w4 + (float)v5[0] * w5 + (float)v6[0] * w6 + (float)v7[0] * w7;
        ay += (float)v0[1] * w0 + (float)v1[1] * w1 + (float)v2[1] * w2 + (float)v3[1] * w3
            + (float)v4[1] * w4 + (float)v5[1] * w5 + (float)v6[1] * w6 + (float)v7[1] * w7;
        den += w0 + w1 + w2 + w3 + w4 + w5 + w6 + w7;
    }
    for (; j + 4 <= r1; j += 4) {
        int s0 = cs[j + 0], s1 = cs[j + 1], s2 = cs[j + 2], s3 = cs[j + 3];
        float p0 = Ss[s0 * sst + sc], p1 = Ss[s1 * sst + sc];
        float p2 = Ss[s2 * sst + sc], p3 = Ss[s3 * sst + sc];
        bf2 v0 = *(const bf2*)&hs[(size_t)s0 * 128 + lane * 2];
        bf2 v1 = *(const bf2*)&hs[(size_t)s1 * 128 + lane * 2];
        bf2 v2 = *(const bf2*)&hs[(size_t)s2 * 128 + lane * 2];
        bf2 v3 = *(const bf2*)&hs[(size_t)s3 * 128 + lane * 2];
        float e0 = p0 + edv; e0 = (e0 >= 0.f) ? e0 : NEG_ * e0;
        float e1 = p1 + edv; e1 = (e1 >= 0.f) ? e1 : NEG_ * e1;
        float e2 = p2 + edv; e2 = (e2 >= 0.f) ? e2 : NEG_ * e2;
        float e3 = p3 + edv; e3 = (e3 >= 0.f) ? e3 : NEG_ * e3;
        float w0 = __expf(e0), w1 = __expf(e1), w2 = __expf(e2), w3 = __expf(e3);
        ax += (float)v0[0] * w0 + (float)v1[0] * w1 + (float)v2[0] * w2 + (float)v3[0] * w3;
        ay += (float)v0[1] * w0 + (float)v1[1] * w1 + (float)v2[1] * w2 + (float)v3[1] * w3;
        den += w0 + w1 + w2 + w3;
    }
    for (; j < r1; ++j) {
        int s = cs[j];
        float p = Ss[s * sst + sc];
        bf2 v = *(const bf2*)&hs[(size_t)s * 128 + lane * 2];
        float e = p + edv; e = (e >= 0.f) ? e : NEG_ * e;
        float w = __expf(e);
        ax += (float)v[0] * w;
        ay += (float)v[1] * w;
        den += w;
    }
    float inv = 1.f / den;
    ox += ax * inv;
    oy += ay * inv;
}

__global__ __launch_bounds__(256) void agg_all(
        const int* __restrict__ row, const int* __restrict__ cs,
        const __bf16* __restrict__ hs_a, const __bf16* __restrict__ hs_b,
        const __bf16* __restrict__ hs_c,
        const float* __restrict__ scR, const float* __restrict__ scV,
        float* __restrict__ o_r, float* __restrict__ o_v,
        float* __restrict__ s4) {
    int b = blockIdx.x;
    // block 0 zeroes s4 for the following bn_stats (agg never reads s4)
    if (b == 0) { s4[threadIdx.x] = 0.f; s4[256 + threadIdx.x] = 0.f; }
    int lane = threadIdx.x & 63;
    int hoff = lane >> 5;
    if (b < AGB_R) {
        int node = b * 4 + (threadIdx.x >> 6);
        if (node >= NR_) return;
        float ed_rr = scR[node * 8 + 2 + hoff];
        float ed_vr = scR[node * 8 + 4 + hoff];
        float ox = 0.f, oy = 0.f;
        agg_rel_bf(node, lane, row, cs, hs_a, scR, 8, 0 + hoff, ed_rr, ox, oy);
        agg_rel_bf(node, lane, row + NR_, cs, hs_b, scV, 4, 0 + hoff, ed_vr, ox, oy);
        *(float2*)&o_r[(size_t)node * 128 + lane * 2] = make_float2(ox * 0.5f, oy * 0.5f);
    } else {
        int node = (b - AGB_R) * 4 + (threadIdx.x >> 6);
        if (node >= NV_) return;
        float ed_rv = scV[node * 4 + 2 + hoff];
        float ox = 0.f, oy = 0.f;
        agg_rel_bf(node, lane, row + 2 * NR_, cs, hs_c, scR, 8, 6 + hoff, ed_rv, ox, oy);
        *(float2*)&o_v[(size_t)node * 128 + lane * 2] = make_float2(ox, oy);
    }
}

// ================= BN stats (standalone, low block count) =================

__global__ __launch_bounds__(256) void bn_stats_all(const float* __restrict__ o_r,
                                                    const float* __restrict__ o_v,
                                                    float* __restrict__ s4) {
    int b = blockIdx.x;
    const float* o; int N; int r0; int soff;
    if (b < BN_BLKS_R) { o = o_r; N = NR_; r0 = b * 64; soff = 0; }
    else               { o = o_v; N = NV_; r0 = (b - BN_BLKS_R) * 64; soff = 128; }
    int wave = threadIdx.x >> 6, lane = threadIdx.x & 63;
    int rend = r0 + 64; if (rend > N) rend = N;
    float sx = 0.f, sy = 0.f, qx = 0.f, qy = 0.f;
    for (int r = r0 + wave; r < rend; r += 4) {
        float2 v = *(const float2*)&o[(size_t)r * 128 + lane * 2];
        sx += v.x; sy += v.y;
        qx += v.x * v.x; qy += v.y * v.y;
    }
    __shared__ float bs[4][128];
    __shared__ float bq[4][128];
    bs[wave][lane * 2] = sx;  bs[wave][lane * 2 + 1] = sy;
    bq[wave][lane * 2] = qx;  bq[wave][lane * 2 + 1] = qy;
    __syncthreads();
    if (threadIdx.x < 128) {
        int c = threadIdx.x;
        float s = bs[0][c] + bs[1][c] + bs[2][c] + bs[3][c];
        float q = bq[0][c] + bq[1][c] + bq[2][c] + bq[3][c];
        atomicAdd(&s4[soff + c], s);
        atomicAdd(&s4[256 + soff + c], q);
    }
}

// ================= BN norm + lrelu + bf16-out + fused next-stage scores (compile-time P) =================

template <int P>
__device__ __forceinline__ void do_bn_norm(int node, int lane, int soff, float invN,
                                           const float* __restrict__ o,
                                           const float* __restrict__ s4,
                                           const float* __restrict__ gammaL,
                                           const float* __restrict__ betaL,
                                           const float* __restrict__ fold,
                                           __bf16* __restrict__ xb,
                                           float* __restrict__ sc) {
    int c0 = lane * 2;
    float f0[P], f1[P];
#pragma unroll
    for (int p = 0; p < P; ++p) {
        f0[p] = fold[c0 * P + p];
        f1[p] = fold[(c0 + 1) * P + p];
    }
    float2 ov = *(const float2*)&o[(size_t)node * 128 + c0];
    float mu0 = s4[soff + c0] * invN,       mu1 = s4[soff + c0 + 1] * invN;
    float q0  = s4[256 + soff + c0] * invN, q1  = s4[256 + soff + c0 + 1] * invN;
    float g0 = gammaL[soff + c0], g1 = gammaL[soff + c0 + 1];
    float b0 = betaL[soff + c0],  b1 = betaL[soff + c0 + 1];
    float v0 = (ov.x - mu0) * rsqrtf(q0 - mu0 * mu0 + EPS_) * g0 + b0;
    float v1 = (ov.y - mu1) * rsqrtf(q1 - mu1 * mu1 + EPS_) * g1 + b1;
    v0 = (v0 >= 0.f) ? v0 : NEG_ * v0;
    v1 = (v1 >= 0.f) ? v1 : NEG_ * v1;
    bf2 w; w[0] = (__bf16)v0; w[1] = (__bf16)v1;
    *(bf2*)&xb[(size_t)node * 128 + c0] = w;
    float part[P];
#pragma unroll
    for (int p = 0; p < P; ++p) part[p] = v0 * f0[p] + v1 * f1[p];
#pragma unroll
    for (int off = 32; off; off >>= 1) {
#pragma unroll
        for (int p = 0; p < P; ++p) part[p] += __shfl_xor(part[p], off);
    }
    if (lane == 0) {
#pragma unroll
        for (int p = 0; p < P; ++p) sc[(size_t)node * P + p] = part[p];
    }
}

template <int PR, int PV>
__global__ __launch_bounds__(256) void bn_norm_fused(
        const float* __restrict__ o_r, const float* __restrict__ o_v,
        const float* __restrict__ s4,
        const float* __restrict__ gammaL, const float* __restrict__ betaL,
        __bf16* __restrict__ xrb, __bf16* __restrict__ xvb,
        const float* __restrict__ foldRn, const float* __restrict__ foldVn,
        float* __restrict__ scRo, float* __restrict__ scVo) {
    int b = blockIdx.x;
    int wave = threadIdx.x >> 6, lane = threadIdx.x & 63;
    if (b < BNN_R) {
        int node = b * 4 + wave;
        if (node >= NR_) return;
        do_bn_norm<PR>(node, lane, 0, 1.f / NR_, o_r, s4, gammaL, betaL, foldRn, xrb, scRo);
    } else {
        int node = (b - BNN_R) * 4 + wave;
        if (node >= NV_) return;
        do_bn_norm<PV>(node, lane, 128, 1.f / NV_, o_v, s4, gammaL, betaL, foldVn, xvb, scVo);
    }
}

// ================= final head =================

__global__ void final_edge_all(const int* __restrict__ ei_rr, const int* __restrict__ ei_vr,
                               const int* __restrict__ ei_rv,
                               const float* __restrict__ ea_rr, const float* __restrict__ ea_vr,
                               const float* __restrict__ ea_rv,
                               const float* __restrict__ ssR, const float* __restrict__ ssV,
                               const float* __restrict__ wp2, const float* __restrict__ cterm,
                               float* __restrict__ out) {
    int j = blockIdx.x * blockDim.x + threadIdx.x;
    if (j >= ETOT_) return;
    int rel, jj;
    const int* src; const int* dst; const float* ea; const float* ss; const float* sd; float* o;
    if (j < ERR_) {
        rel = 0; jj = j; src = ei_rr; dst = ei_rr + ERR_; ea = ea_rr; ss = ssR; sd = ssR; o = out;
    } else if (j < ERR_ + EVR_) {
        rel = 1; jj = j - ERR_; src = ei_vr; dst = ei_vr + EVR_; ea = ea_vr; ss = ssV; sd = ssR;
        o = out + (size_t)ERR_ * 2;
    } else {
        rel = 2; jj = j - ERR_ - EVR_; src = ei_rv; dst = ei_rv + ERV_; ea = ea_rv; ss = ssR; sd = ssV;
        o = out + (size_t)(ERR_ + EVR_) * 2;
    }
    int s = src[jj], d = dst[jj];
    float l0 = ss[s * 4 + 0] + sd[d * 4 + 2] + cterm[rel * 2 + 0];
    float l1 = ss[s * 4 + 1] + sd[d * 4 + 3] + cterm[rel * 2 + 1];
    const float* w = wp2 + rel * 16;
#pragma unroll
    for (int k = 0; k < 8; ++k) {
        float v = ea[(size_t)jj * 8 + k];
        l0 += v * w[k * 2 + 0];
        l1 += v * w[k * 2 + 1];
    }
    float m = fmaxf(l0, l1);
    float p0 = __expf(l0 - m), p1 = __expf(l1 - m);
    float inv = 1.f / (p0 + p1);
    o[(size_t)jj * 2 + 0] = p0 * inv;
    o[(size_t)jj * 2 + 1] = p1 * inv;
}

// ================= host orchestration (13 dispatches + 1 memset) =================

extern "C" void kernel_launch(void* const* d_in, const int* in_sizes, int n_in,
                              void* d_out, int out_size, void* d_ws, size_t ws_size,
                              hipStream_t stream) {
    const float* x_req = (const float*)d_in[0];
    const float* x_veh = (const float*)d_in[1];
    const int* ei_rr = (const int*)d_in[2];
    const int* ei_vr = (const int*)d_in[3];
    const int* ei_rv = (const int*)d_in[4];
    const float* ea_rr = (const float*)d_in[5];
    const float* ea_vr = (const float*)d_in[6];
    const float* ea_rv = (const float*)d_in[7];
    const float* Wsrc1 = (const float*)d_in[8];
    const float* Wdst1 = (const float*)d_in[9];
    const float* asrc1 = (const float*)d_in[10];
    const float* adst1 = (const float*)d_in[11];
    const float* Wsrc2 = (const float*)d_in[13];
    const float* Wdst2 = (const float*)d_in[14];
    const float* asrc2 = (const float*)d_in[15];
    const float* adst2 = (const float*)d_in[16];
    const float* bn_gamma = (const float*)d_in[18];
    const float* bn_beta  = (const float*)d_in[19];
    const float* Wp   = (const float*)d_in[20];
    const float* bp   = (const float*)d_in[21];
    const float* Wlin = (const float*)d_in[22];
    const float* blin = (const float*)d_in[23];
    float* out = (float*)d_out;

    float* w = (float*)d_ws;
    size_t off = 0;
    float* o_r   = w + off; off += (size_t)NR_ * 128;
    float* o_v   = w + off; off += (size_t)NV_ * 128;
    float* scR   = w + off; off += (size_t)NR_ * 8;
    float* scV   = w + off; off += (size_t)NV_ * 4;
    float* s4    = w + off; off += 512;
    float* foldR = w + off; off += 2 * 128 * 8;
    float* foldV = w + off; off += 2 * 128 * 4;
    float* wp2   = w + off; off += 48;
    float* cterm = w + off; off += 8;
    float* fw    = w + off; off += 512;
    float* ssR   = w + off; off += (size_t)NR_ * 4;
    float* ssV   = w + off; off += (size_t)NV_ * 4;
    __bf16* hs_a = (__bf16*)(w + off); off += (size_t)NR_ * 128 / 2;
    __bf16* hs_b = (__bf16*)(w + off); off += (size_t)NV_ * 128 / 2;
    __bf16* hs_c = (__bf16*)(w + off); off += (size_t)NR_ * 128 / 2;
    __bf16* xrb  = (__bf16*)(w + off); off += (size_t)NR_ * 128 / 2;
    __bf16* xvb  = (__bf16*)(w + off); off += (size_t)NV_ * 128 / 2;
    __bf16* Wt   = (__bf16*)(w + off); off += 3 * 128 * 128 / 2;
    int* iw = (int*)(w + off);
    size_t ioff = 0;
    int* row  = iw + ioff; ioff += NTOT_ + 1;
    int* cur  = iw + ioff; ioff += NTOT_;
    int* bsum = iw + ioff; ioff += SCAN_NB;
    int* cs   = iw + ioff; ioff += ETOT_;

    // cnt (=cur) must be zero before hist (inside precompute_hist)
    hipMemsetAsync(cur, 0, NTOT_ * sizeof(int), stream);
    precompute_hist<<<PREB + HISTB, 256, 0, stream>>>(
        Wsrc1, Wdst1, asrc1, adst1, Wsrc2, Wdst2, asrc2, adst2,
        Wp, bp, Wlin, blin, ei_rr, ei_vr, ei_rv,
        foldR, foldV, wp2, cterm, fw, Wt, cur);

    scan_reduce<<<SCAN_NB, 256, 0, stream>>>(cur, bsum);
    scan_write<<<SCAN_NB, 256, 0, stream>>>(cur, bsum, row, cur);
    scatter_gemm_l1<<<L1B_TOT + HISTB, 256, 0, stream>>>(
        ei_rr, ei_vr, ei_rv, cur, cs,
        x_req, x_veh, Wsrc1, foldR, foldV, hs_a, hs_b, hs_c, scR, scV);

    for (int l = 0; l < 2; ++l) {
        if (l == 1) {
            gemm_mfma_all<<<2 * MFB_R + MFB_V, 256, 0, stream>>>(xrb, xvb, Wt, hs_a, hs_b, hs_c);
        }
        agg_all<<<AGB_R + AGB_V, 256, 0, stream>>>(row, cs, hs_a, hs_b, hs_c, scR, scV, o_r, o_v, s4);
        bn_stats_all<<<BN_BLKS_R + BN_BLKS_V, 256, 0, stream>>>(o_r, o_v, s4);
        if (l == 0) {
            bn_norm_fused<8, 4><<<BNN_R + BNN_V, 256, 0, stream>>>(
                o_r, o_v, s4, bn_gamma, bn_beta, xrb, xvb,
                foldR + 1024, foldV + 512, scR, scV);
        } else {
            bn_norm_fused<4, 4><<<BNN_R + BNN_V, 256, 0, stream>>>(
                o_r, o_v, s4, bn_gamma + 256, bn_beta + 256, xrb, xvb,
                fw, fw, ssR, ssV);
        }
    }

    final_edge_all<<<(ETOT_ + 255) / 256, 256, 0, stream>>>(ei_rr, ei_vr, ei_rv, ea_rr, ea_vr, ea_rv,
                                                            ssR, ssV, wp2, cterm, out);
}

// Round 16
// 393.315 us; speedup vs baseline: 1.0913x; 1.0913x over previous
//
#include <hip/hip_runtime.h>
#include <hip/hip_bf16.h>

#define NR_ 40000
#define NV_ 4000
#define ERR_ 400000
#define EVR_ 150000
#define ERV_ 150000
#define ETOT_ (ERR_ + EVR_ + ERV_)
#define NTOT_ (NR_ + NR_ + NV_)
#define SCAN_ELEMS 512
#define SCAN_NB ((NTOT_ + SCAN_ELEMS - 1) / SCAN_ELEMS)   // 165
#define BN_BLKS_R ((NR_ + 63) / 64)  // 625
#define BN_BLKS_V ((NV_ + 63) / 64)  // 63
#define L1B_R ((NR_ + 31) / 32)      // 1250
#define L1B_V ((NV_ + 31) / 32)      // 125
#define MFB_R ((NR_ + 63) / 64)      // 625
#define MFB_V ((NV_ + 63) / 64)      // 63
#define AGB_R ((NR_ + 3) / 4)        // 10000
#define AGB_V ((NV_ + 3) / 4)        // 1000
#define BNN_R ((NR_ + 3) / 4)
#define BNN_V ((NV_ + 3) / 4)
#define HISTB ((ETOT_ + 255) / 256)  // 2735
#define PREB (14 + 192)              // fold/misc blocks + Wt blocks
#define NEG_ 0.2f
#define EPS_ 1e-5f

typedef __attribute__((ext_vector_type(8))) __bf16 bfrag;
typedef __attribute__((ext_vector_type(4))) float ffrag;
typedef __attribute__((ext_vector_type(4))) __bf16 bf4;
typedef __attribute__((ext_vector_type(2))) __bf16 bf2;

// ============ precompute (folds, wp2, fw, Wt) + hist-with-rank, one launch ============

__global__ __launch_bounds__(256) void precompute_hist(
        const float* __restrict__ Wsrc1, const float* __restrict__ Wdst1,
        const float* __restrict__ asrc1, const float* __restrict__ adst1,
        const float* __restrict__ Wsrc2, const float* __restrict__ Wdst2,
        const float* __restrict__ asrc2, const float* __restrict__ adst2,
        const float* __restrict__ Wp, const float* __restrict__ bp,
        const float* __restrict__ Wlin, const float* __restrict__ blin,
        const int* __restrict__ ei_rr, const int* __restrict__ ei_vr, const int* __restrict__ ei_rv,
        float* __restrict__ foldR, float* __restrict__ foldV,
        float* __restrict__ wp2, float* __restrict__ cterm,
        float* __restrict__ fw, __bf16* __restrict__ Wt,
        int* __restrict__ cnt, int* __restrict__ rank) {
    int b = blockIdx.x;
    int t = threadIdx.x;
    if (b < 12) {
        int layer = b / 6, rel = (b % 6) / 2, side = b & 1;
        int K = (layer == 0) ? 16 : 128;
        const float* W = (layer == 0) ? (side ? Wdst1 : Wsrc1) : (side ? Wdst2 : Wsrc2);
        const float* a = (layer == 0) ? (side ? adst1 : asrc1) : (side ? adst2 : asrc2);
        W += (size_t)rel * K * 128;
        a += rel * 128;
        float* dst; int P; int colbase;
        if (rel == 0 && side == 0)      { dst = foldR; P = 8; colbase = 0; }
        else if (rel == 0)              { dst = foldR; P = 8; colbase = 2; }
        else if (rel == 1 && side == 0) { dst = foldV; P = 4; colbase = 0; }
        else if (rel == 1)              { dst = foldR; P = 8; colbase = 4; }
        else if (side == 0)             { dst = foldR; P = 8; colbase = 6; }
        else                            { dst = foldV; P = 4; colbase = 2; }
        dst += (size_t)layer * 128 * P;
        if (t < K) {
            for (int h = 0; h < 2; ++h) {
                float s = 0.f;
                for (int c = 0; c < 64; ++c) s += W[t * 128 + h * 64 + c] * a[h * 64 + c];
                dst[t * P + colbase + h] = s;
            }
        }
    } else if (b == 12) {
        if (t < 48) {
            int i = t / 16, k = (t / 2) % 8, o = t & 1;
            float s = 0.f;
            for (int c = 0; c < 64; ++c) s += Wp[(i * 8 + k) * 64 + c] * Wlin[(128 + c) * 2 + o];
            wp2[t] = s;
        } else if (t < 54) {
            int i = (t - 48) / 2, o = (t - 48) & 1;
            float s = blin[o];
            for (int c = 0; c < 64; ++c) s += bp[i * 64 + c] * Wlin[(128 + c) * 2 + o];
            cterm[i * 2 + o] = s;
        }
    } else if (b == 13) {
        for (int idx = t; idx < 512; idx += 256) {
            int k = idx >> 2, c = idx & 3;
            fw[idx] = Wlin[(k + ((c >= 2) ? 192 : 0)) * 2 + (c & 1)];
        }
    } else if (b < PREB) {
        int i = (b - 14) * 256 + t;
        if (i < 3 * 128 * 128) {
            int rel = i >> 14, rem = i & 16383, n = rem >> 7, k = rem & 127;
            Wt[i] = (__bf16)Wsrc2[(size_t)rel * 16384 + k * 128 + n];
        }
    } else {
        int j = (b - PREB) * 256 + t;
        int nidx;
        if (j < ERR_) nidx = ei_rr[ERR_ + j];
        else if (j < ERR_ + EVR_) nidx = NR_ + ei_vr[EVR_ + (j - ERR_)];
        else if (j < ETOT_) nidx = 2 * NR_ + ei_rv[ERV_ + (j - ERR_ - EVR_)];
        else return;
        rank[j] = atomicAdd(&cnt[nidx], 1);
    }
}

// ============ scan: reduce + write (write-block computes its own offset) ============

__global__ __launch_bounds__(256) void scan_reduce(const int* __restrict__ cnt, int* __restrict__ bsum) {
    __shared__ int buf[256];
    int t = threadIdx.x;
    int i0 = blockIdx.x * SCAN_ELEMS + t * 2;
    int s = 0;
    if (i0 + 1 < NTOT_) { int2 v = *(const int2*)&cnt[i0]; s = v.x + v.y; }
    else if (i0 < NTOT_) s = cnt[i0];
    buf[t] = s;
    __syncthreads();
    for (int off = 128; off; off >>= 1) {
        if (t < off) buf[t] += buf[t + off];
        __syncthreads();
    }
    if (t == 0) bsum[blockIdx.x] = buf[0];
}

__global__ __launch_bounds__(256) void scan_write(const int* __restrict__ cnt,
                                                  const int* __restrict__ bsum,
                                                  int* __restrict__ row) {
    __shared__ int rbuf[256];
    __shared__ int buf[256];
    int t = threadIdx.x;
    int sb = (t < SCAN_NB && t < (int)blockIdx.x) ? bsum[t] : 0;
    rbuf[t] = sb;
    __syncthreads();
    for (int off = 128; off; off >>= 1) {
        if (t < off) rbuf[t] += rbuf[t + off];
        __syncthreads();
    }
    int boff = rbuf[0];

    int i0 = blockIdx.x * SCAN_ELEMS + t * 2;
    int vx = 0, vy = 0;
    if (i0 + 1 < NTOT_) { int2 v = *(const int2*)&cnt[i0]; vx = v.x; vy = v.y; }
    else if (i0 < NTOT_) vx = cnt[i0];
    int s = vx + vy;
    buf[t] = s;
    __syncthreads();
    for (int off = 1; off < 256; off <<= 1) {
        int v = (t >= off) ? buf[t - off] : 0;
        __syncthreads();
        buf[t] += v;
        __syncthreads();
    }
    int ex = buf[t] - s + boff;
    if (i0 + 1 < NTOT_) {
        *(int2*)&row[i0] = make_int2(ex, ex + vx);
    } else if (i0 < NTOT_) {
        row[i0] = ex;
    }
    if (blockIdx.x == 0 && t == 0) row[NTOT_] = ETOT_;
}

// ============ scatter: ATOMIC-FREE (slot = row[nidx] + rank[j]) ============

__global__ void scatter_all(const int* __restrict__ ei_rr, const int* __restrict__ ei_vr,
                            const int* __restrict__ ei_rv,
                            const int* __restrict__ row, const int* __restrict__ rank,
                            int* __restrict__ cs) {
    int j = blockIdx.x * blockDim.x + threadIdx.x;
    int s, nidx;
    if (j < ERR_)             { s = ei_rr[j]; nidx = ei_rr[ERR_ + j]; }
    else if (j < ERR_ + EVR_) { int jj = j - ERR_; s = ei_vr[jj]; nidx = NR_ + ei_vr[EVR_ + jj]; }
    else if (j < ETOT_)       { int jj = j - ERR_ - EVR_; s = ei_rv[jj]; nidx = 2 * NR_ + ei_rv[ERV_ + jj]; }
    else return;
    cs[row[nidx] + rank[j]] = s;
}

// ===== layer-1: all 3 projections (K=16) + fused scores, bf16 hs out =====

__global__ __launch_bounds__(256) void gemm_l1_all(const float* __restrict__ x_req,
                                                   const float* __restrict__ x_veh,
                                                   const float* __restrict__ W,
                                                   const float* __restrict__ fR, const float* __restrict__ fV,
                                                   __bf16* __restrict__ hs_a, __bf16* __restrict__ hs_b,
                                                   __bf16* __restrict__ hs_c,
                                                   float* __restrict__ scR, float* __restrict__ scV) {
    __shared__ float xs[32][20];
    __shared__ float ws[16][128];
    __shared__ float fs[128];
    int b = blockIdx.x;
    int t = threadIdx.x;
    const float* x; const float* Wr; const float* fold; __bf16* hs; float* sc; int N, P, row0;
    if (b < L1B_R)          { x = x_req; Wr = W + 0 * 2048; fold = fR; hs = hs_a; sc = scR; N = NR_; P = 8; row0 = b * 32; }
    else if (b < 2 * L1B_R) { x = x_req; Wr = W + 2 * 2048; fold = nullptr; hs = hs_c; sc = nullptr; N = NR_; P = 0; row0 = (b - L1B_R) * 32; }
    else                    { x = x_veh; Wr = W + 1 * 2048; fold = fV; hs = hs_b; sc = scV; N = NV_; P = 4; row0 = (b - 2 * L1B_R) * 32; }

    for (int v = t; v < 32 * 4; v += 256) {
        int r = v >> 2, kk = (v & 3) * 4;
        int rr = row0 + r;
        float4 val = make_float4(0.f, 0.f, 0.f, 0.f);
        if (rr < N) val = *(const float4*)&x[(size_t)rr * 16 + kk];
        *(float4*)&xs[r][kk] = val;
    }
    for (int v = t; v < 512; v += 256) ((float4*)&ws[0][0])[v] = ((const float4*)Wr)[v];
    if (P > 0)
        for (int v = t; v < 16 * P; v += 256) fs[v] = fold[v];
    __syncthreads();

    int cg4 = (t & 31) * 4;
    int rg4 = (t >> 5) * 4;
    float acc[4][4] = {{0.f}};
#pragma unroll
    for (int k = 0; k < 16; k += 4) {
        float4 xv[4];
#pragma unroll
        for (int i = 0; i < 4; ++i) xv[i] = *(const float4*)&xs[rg4 + i][k];
        float4 w0 = *(const float4*)&ws[k + 0][cg4];
        float4 w1 = *(const float4*)&ws[k + 1][cg4];
        float4 w2 = *(const float4*)&ws[k + 2][cg4];
        float4 w3 = *(const float4*)&ws[k + 3][cg4];
#pragma unroll
        for (int i = 0; i < 4; ++i) {
            acc[i][0] += xv[i].x * w0.x + xv[i].y * w1.x + xv[i].z * w2.x + xv[i].w * w3.x;
            acc[i][1] += xv[i].x * w0.y + xv[i].y * w1.y + xv[i].z * w2.y + xv[i].w * w3.y;
            acc[i][2] += xv[i].x * w0.z + xv[i].y * w1.z + xv[i].z * w2.z + xv[i].w * w3.z;
            acc[i][3] += xv[i].x * w0.w + xv[i].y * w1.w + xv[i].z * w2.w + xv[i].w * w3.w;
        }
    }
#pragma unroll
    for (int i = 0; i < 4; ++i) {
        int rr = row0 + rg4 + i;
        if (rr < N) {
            bf4 o;
            o[0] = (__bf16)acc[i][0]; o[1] = (__bf16)acc[i][1];
            o[2] = (__bf16)acc[i][2]; o[3] = (__bf16)acc[i][3];
            *(bf4*)&hs[(size_t)rr * 128 + cg4] = o;
        }
    }
    if (P > 0 && t < 32 * P) {
        int srow = t / P, scol = t % P;
        if (row0 + srow < N) {
            float s = 0.f;
            for (int k = 0; k < 16; ++k) s += xs[srow][k] * fs[k * P + scol];
            sc[(size_t)(row0 + srow) * P + scol] = s;
        }
    }
}

// ===== layer-2: all 3 projections via bf16 MFMA =====

__global__ __launch_bounds__(256) void gemm_mfma_all(const __bf16* __restrict__ xrb,
                                                     const __bf16* __restrict__ xvb,
                                                     const __bf16* __restrict__ Wt,
                                                     __bf16* __restrict__ hs_a, __bf16* __restrict__ hs_b,
                                                     __bf16* __restrict__ hs_c) {
    int b = blockIdx.x;
    const __bf16* x; const __bf16* W; __bf16* hs; int N, blk;
    if (b < MFB_R)          { x = xrb; W = Wt + 0 * 16384; hs = hs_a; N = NR_; blk = b; }
    else if (b < 2 * MFB_R) { x = xrb; W = Wt + 2 * 16384; hs = hs_c; N = NR_; blk = b - MFB_R; }
    else                    { x = xvb; W = Wt + 1 * 16384; hs = hs_b; N = NV_; blk = b - 2 * MFB_R; }
    int wave = threadIdx.x >> 6;
    int lane = threadIdx.x & 63;
    int m = lane & 15;
    int quad = lane >> 4;
    int row0 = blk * 64 + wave * 16;
    int arow = row0 + m;
    int rs = (arow < N) ? arow : (N - 1);
    const __bf16* xp = x + (size_t)rs * 128 + quad * 8;
    bfrag A0 = *(const bfrag*)(xp);
    bfrag A1 = *(const bfrag*)(xp + 32);
    bfrag A2 = *(const bfrag*)(xp + 64);
    bfrag A3 = *(const bfrag*)(xp + 96);
#pragma unroll
    for (int nt = 0; nt < 8; ++nt) {
        const __bf16* wp = W + (size_t)(nt * 16 + m) * 128 + quad * 8;
        ffrag acc = {0.f, 0.f, 0.f, 0.f};
        acc = __builtin_amdgcn_mfma_f32_16x16x32_bf16(A0, *(const bfrag*)(wp), acc, 0, 0, 0);
        acc = __builtin_amdgcn_mfma_f32_16x16x32_bf16(A1, *(const bfrag*)(wp + 32), acc, 0, 0, 0);
        acc = __builtin_amdgcn_mfma_f32_16x16x32_bf16(A2, *(const bfrag*)(wp + 64), acc, 0, 0, 0);
        acc = __builtin_amdgcn_mfma_f32_16x16x32_bf16(A3, *(const bfrag*)(wp + 96), acc, 0, 0, 0);
        int dcol = nt * 16 + m;
#pragma unroll
        for (int r = 0; r < 4; ++r) {
            int drow = row0 + quad * 4 + r;
            if (drow < N) hs[(size_t)drow * 128 + dcol] = (__bf16)acc[r];
        }
    }
}

// ============ gather-aggregate (bf16 hs), fused softmax; bf16 o out; block 0 zeroes s4 ============

__device__ __forceinline__ void agg_rel_bf(int node, int lane,
                                           const int* __restrict__ row, const int* __restrict__ cs,
                                           const __bf16* __restrict__ hs,
                                           const float* __restrict__ Ss, int sst, int sc, float edv,
                                           float& ox, float& oy) {
    int r0 = row[node], r1 = row[node + 1];
    if (r1 <= r0) return;
    float ax = 0.f, ay = 0.f, den = 0.f;
    int j = r0;
    for (; j + 8 <= r1; j += 8) {
        int s0 = cs[j + 0], s1 = cs[j + 1], s2 = cs[j + 2], s3 = cs[j + 3];
        int s4_ = cs[j + 4], s5 = cs[j + 5], s6 = cs[j + 6], s7 = cs[j + 7];
        float p0 = Ss[s0 * sst + sc], p1 = Ss[s1 * sst + sc];
        float p2 = Ss[s2 * sst + sc], p3 = Ss[s3 * sst + sc];
        float p4 = Ss[s4_ * sst + sc], p5 = Ss[s5 * sst + sc];
        float p6 = Ss[s6 * sst + sc], p7 = Ss[s7 * sst + sc];
        bf2 v0 = *(const bf2*)&hs[(size_t)s0 * 128 + lane * 2];
        bf2 v1 = *(const bf2*)&hs[(size_t)s1 * 128 + lane * 2];
        bf2 v2 = *(const bf2*)&hs[(size_t)s2 * 128 + lane * 2];
        bf2 v3 = *(const bf2*)&hs[(size_t)s3 * 128 + lane * 2];
        bf2 v4 = *(const bf2*)&hs[(size_t)s4_ * 128 + lane * 2];
        bf2 v5 = *(const bf2*)&hs[(size_t)s5 * 128 + lane * 2];
        bf2 v6 = *(const bf2*)&hs[(size_t)s6 * 128 + lane * 2];
        bf2 v7 = *(const bf2*)&hs[(size_t)s7 * 128 + lane * 2];
        float e0 = p0 + edv; e0 = (e0 >= 0.f) ? e0 : NEG_ * e0;
        float e1 = p1 + edv; e1 = (e1 >= 0.f) ? e1 : NEG_ * e1;
        float e2 = p2 + edv; e2 = (e2 >= 0.f) ? e2 : NEG_ * e2;
        float e3 = p3 + edv; e3 = (e3 >= 0.f) ? e3 : NEG_ * e3;
        float e4 = p4 + edv; e4 = (e4 >= 0.f) ? e4 : NEG_ * e4;
        float e5 = p5 + edv; e5 = (e5 >= 0.f) ? e5 : NEG_ * e5;
        float e6 = p6 + edv; e6 = (e6 >= 0.f) ? e6 : NEG_ * e6;
        float e7 = p7 + edv; e7 = (e7 >= 0.f) ? e7 : NEG_ * e7;
        float w0 = __expf(e0), w1 = __expf(e1), w2 = __expf(e2), w3 = __expf(e3);
        float w4 = __expf(e4), w5 = __expf(e5), w6 = __expf(e6), w7 = __expf(e7);
        ax += (float)v0[0] * w0 + (float)v1[0] * w1 + (float)v2[0] * w2 + (float)v3[0] * w3
            + (float)v4[0] * w4 + (float)v5[0] * w5 + (float)v6[0] * w6 + (float)v7[0] * w7;
        ay += (float)v0[1] * w0 + (float)v1[1] * w1 + (float)v2[1] * w2 + (float)v3[1] * w3
            + (float)v4[1] * w4 + (float)v5[1] * w5 + (float)v6[1] * w6 + (float)v7[1] * w7;
        den += w0 + w1 + w2 + w3 + w4 + w5 + w6 + w7;
    }
    for (; j + 4 <= r1; j += 4) {
        int s0 = cs[j + 0], s1 = cs[j + 1], s2 = cs[j + 2], s3 = cs[j + 3];
        float p0 = Ss[s0 * sst + sc], p1 = Ss[s1 * sst + sc];
        float p2 = Ss[s2 * sst + sc], p3 = Ss[s3 * sst + sc];
        bf2 v0 = *(const bf2*)&hs[(size_t)s0 * 128 + lane * 2];
        bf2 v1 = *(const bf2*)&hs[(size_t)s1 * 128 + lane * 2];
        bf2 v2 = *(const bf2*)&hs[(size_t)s2 * 128 + lane * 2];
        bf2 v3 = *(const bf2*)&hs[(size_t)s3 * 128 + lane * 2];
        float e0 = p0 + edv; e0 = (e0 >= 0.f) ? e0 : NEG_ * e0;
        float e1 = p1 + edv; e1 = (e1 >= 0.f) ? e1 : NEG_ * e1;
        float e2 = p2 + edv; e2 = (e2 >= 0.f) ? e2 : NEG_ * e2;
        float e3 = p3 + edv; e3 = (e3 >= 0.f) ? e3 : NEG_ * e3;
        float w0 = __expf(e0), w1 = __expf(e1), w2 = __expf(e2), w3 = __expf(e3);
        ax += (float)v0[0] * w0 + (float)v1[0] * w1 + (float)v2[0] * w2 + (float)v3[0] * w3;
        ay += (float)v0[1] * w0 + (float)v1[1] * w1 + (float)v2[1] * w2 + (float)v3[1] * w3;
        den += w0 + w1 + w2 + w3;
    }
    for (; j < r1; ++j) {
        int s = cs[j];
        float p = Ss[s * sst + sc];
        bf2 v = *(const bf2*)&hs[(size_t)s * 128 + lane * 2];
        float e = p + edv; e = (e >= 0.f) ? e : NEG_ * e;
        float w = __expf(e);
        ax += (float)v[0] * w;
        ay += (float)v[1] * w;
        den += w;
    }
    float inv = 1.f / den;
    ox += ax * inv;
    oy += ay * inv;
}

__global__ __launch_bounds__(256) void agg_all(
        const int* __restrict__ row, const int* __restrict__ cs,
        const __bf16* __restrict__ hs_a, const __bf16* __restrict__ hs_b,
        const __bf16* __restrict__ hs_c,
        const float* __restrict__ scR, const float* __restrict__ scV,
        __bf16* __restrict__ o_r, __bf16* __restrict__ o_v,
        float* __restrict__ s4) {
    int b = blockIdx.x;
    if (b == 0) { s4[threadIdx.x] = 0.f; s4[256 + threadIdx.x] = 0.f; }
    int lane = threadIdx.x & 63;
    int hoff = lane >> 5;
    if (b < AGB_R) {
        int node = b * 4 + (threadIdx.x >> 6);
        if (node >= NR_) return;
        float ed_rr = scR[node * 8 + 2 + hoff];
        float ed_vr = scR[node * 8 + 4 + hoff];
        float ox = 0.f, oy = 0.f;
        agg_rel_bf(node, lane, row, cs, hs_a, scR, 8, 0 + hoff, ed_rr, ox, oy);
        agg_rel_bf(node, lane, row + NR_, cs, hs_b, scV, 4, 0 + hoff, ed_vr, ox, oy);
        bf2 w; w[0] = (__bf16)(ox * 0.5f); w[1] = (__bf16)(oy * 0.5f);
        *(bf2*)&o_r[(size_t)node * 128 + lane * 2] = w;
    } else {
        int node = (b - AGB_R) * 4 + (threadIdx.x >> 6);
        if (node >= NV_) return;
        float ed_rv = scV[node * 4 + 2 + hoff];
        float ox = 0.f, oy = 0.f;
        agg_rel_bf(node, lane, row + 2 * NR_, cs, hs_c, scR, 8, 6 + hoff, ed_rv, ox, oy);
        bf2 w; w[0] = (__bf16)ox; w[1] = (__bf16)oy;
        *(bf2*)&o_v[(size_t)node * 128 + lane * 2] = w;
    }
}

// ============ BN stats (bf16 o in) ============

__global__ __launch_bounds__(256) void bn_stats_all(const __bf16* __restrict__ o_r,
                                                    const __bf16* __restrict__ o_v,
                                                    float* __restrict__ s4) {
    int b = blockIdx.x;
    const __bf16* o; int N; int r0; int soff;
    if (b < BN_BLKS_R) { o = o_r; N = NR_; r0 = b * 64; soff = 0; }
    else               { o = o_v; N = NV_; r0 = (b - BN_BLKS_R) * 64; soff = 128; }
    int wave = threadIdx.x >> 6, lane = threadIdx.x & 63;
    int rend = r0 + 64; if (rend > N) rend = N;
    float sx = 0.f, sy = 0.f, qx = 0.f, qy = 0.f;
    for (int r = r0 + wave; r < rend; r += 4) {
        bf2 v = *(const bf2*)&o[(size_t)r * 128 + lane * 2];
        float vx = (float)v[0], vy = (float)v[1];
        sx += vx; sy += vy;
        qx += vx * vx; qy += vy * vy;
    }
    __shared__ float bs[4][128];
    __shared__ float bq[4][128];
    bs[wave][lane * 2] = sx;  bs[wave][lane * 2 + 1] = sy;
    bq[wave][lane * 2] = qx;  bq[wave][lane * 2 + 1] = qy;
    __syncthreads();
    if (threadIdx.x < 128) {
        int c = threadIdx.x;
        float s = bs[0][c] + bs[1][c] + bs[2][c] + bs[3][c];
        float q = bq[0][c] + bq[1][c] + bq[2][c] + bq[3][c];
        atomicAdd(&s4[soff + c], s);
        atomicAdd(&s4[256 + soff + c], q);
    }
}

// ============ BN norm + lrelu + bf16-out + fused next-stage scores (compile-time P) ============

template <int P>
__device__ __forceinline__ void do_bn_norm(int node, int lane, int soff, float invN,
                                           const __bf16* __restrict__ o,
                                           const float* __restrict__ s4,
                                           const float* __restrict__ gammaL,
                                           const float* __restrict__ betaL,
                                           const float* __restrict__ fold,
                                           __bf16* __restrict__ xb,
                                           float* __restrict__ sc) {
    int c0 = lane * 2;
    float f0[P], f1[P];
#pragma unroll
    for (int p = 0; p < P; ++p) {
        f0[p] = fold[c0 * P + p];
        f1[p] = fold[(c0 + 1) * P + p];
    }
    bf2 ovb = *(const bf2*)&o[(size_t)node * 128 + c0];
    float ovx = (float)ovb[0], ovy = (float)ovb[1];
    float mu0 = s4[soff + c0] * invN,       mu1 = s4[soff + c0 + 1] * invN;
    float q0  = s4[256 + soff + c0] * invN, q1  = s4[256 + soff + c0 + 1] * invN;
    float g0 = gammaL[soff + c0], g1 = gammaL[soff + c0 + 1];
    float b0 = betaL[soff + c0],  b1 = betaL[soff + c0 + 1];
    float v0 = (ovx - mu0) * rsqrtf(q0 - mu0 * mu0 + EPS_) * g0 + b0;
    float v1 = (ovy - mu1) * rsqrtf(q1 - mu1 * mu1 + EPS_) * g1 + b1;
    v0 = (v0 >= 0.f) ? v0 : NEG_ * v0;
    v1 = (v1 >= 0.f) ? v1 : NEG_ * v1;
    bf2 w; w[0] = (__bf16)v0; w[1] = (__bf16)v1;
    *(bf2*)&xb[(size_t)node * 128 + c0] = w;
    float part[P];
#pragma unroll
    for (int p = 0; p < P; ++p) part[p] = v0 * f0[p] + v1 * f1[p];
#pragma unroll
    for (int off = 32; off; off >>= 1) {
#pragma unroll
        for (int p = 0; p < P; ++p) part[p] += __shfl_xor(part[p], off);
    }
    if (lane == 0) {
#pragma unroll
        for (int p = 0; p < P; ++p) sc[(size_t)node * P + p] = part[p];
    }
}

template <int PR, int PV>
__global__ __launch_bounds__(256) void bn_norm_fused(
        const __bf16* __restrict__ o_r, const __bf16* __restrict__ o_v,
        const float* __restrict__ s4,
        const float* __restrict__ gammaL, const float* __restrict__ betaL,
        __bf16* __restrict__ xrb, __bf16* __restrict__ xvb,
        const float* __restrict__ foldRn, const float* __restrict__ foldVn,
        float* __restrict__ scRo, float* __restrict__ scVo) {
    int b = blockIdx.x;
    int wave = threadIdx.x >> 6, lane = threadIdx.x & 63;
    if (b < BNN_R) {
        int node = b * 4 + wave;
        if (node >= NR_) return;
        do_bn_norm<PR>(node, lane, 0, 1.f / NR_, o_r, s4, gammaL, betaL, foldRn, xrb, scRo);
    } else {
        int node = (b - BNN_R) * 4 + wave;
        if (node >= NV_) return;
        do_bn_norm<PV>(node, lane, 128, 1.f / NV_, o_v, s4, gammaL, betaL, foldVn, xvb, scVo);
    }
}

// ============ final head ============

__global__ void final_edge_all(const int* __restrict__ ei_rr, const int* __restrict__ ei_vr,
                               const int* __restrict__ ei_rv,
                               const float* __restrict__ ea_rr, const float* __restrict__ ea_vr,
                               const float* __restrict__ ea_rv,
                               const float* __restrict__ ssR, const float* __restrict__ ssV,
                               const float* __restrict__ wp2, const float* __restrict__ cterm,
                               float* __restrict__ out) {
    int j = blockIdx.x * blockDim.x + threadIdx.x;
    if (j >= ETOT_) return;
    int rel, jj;
    const int* src; const int* dst; const float* ea; const float* ss; const float* sd; float* o;
    if (j < ERR_) {
        rel = 0; jj = j; src = ei_rr; dst = ei_rr + ERR_; ea = ea_rr; ss = ssR; sd = ssR; o = out;
    } else if (j < ERR_ + EVR_) {
        rel = 1; jj = j - ERR_; src = ei_vr; dst = ei_vr + EVR_; ea = ea_vr; ss = ssV; sd = ssR;
        o = out + (size_t)ERR_ * 2;
    } else {
        rel = 2; jj = j - ERR_ - EVR_; src = ei_rv; dst = ei_rv + ERV_; ea = ea_rv; ss = ssR; sd = ssV;
        o = out + (size_t)(ERR_ + EVR_) * 2;
    }
    int s = src[jj], d = dst[jj];
    float l0 = ss[s * 4 + 0] + sd[d * 4 + 2] + cterm[rel * 2 + 0];
    float l1 = ss[s * 4 + 1] + sd[d * 4 + 3] + cterm[rel * 2 + 1];
    const float* w = wp2 + rel * 16;
#pragma unroll
    for (int k = 0; k < 8; ++k) {
        float v = ea[(size_t)jj * 8 + k];
        l0 += v * w[k * 2 + 0];
        l1 += v * w[k * 2 + 1];
    }
    float m = fmaxf(l0, l1);
    float p0 = __expf(l0 - m), p1 = __expf(l1 - m);
    float inv = 1.f / (p0 + p1);
    o[(size_t)jj * 2 + 0] = p0 * inv;
    o[(size_t)jj * 2 + 1] = p1 * inv;
}

// ============ host orchestration ============

extern "C" void kernel_launch(void* const* d_in, const int* in_sizes, int n_in,
                              void* d_out, int out_size, void* d_ws, size_t ws_size,
                              hipStream_t stream) {
    const float* x_req = (const float*)d_in[0];
    const float* x_veh = (const float*)d_in[1];
    const int* ei_rr = (const int*)d_in[2];
    const int* ei_vr = (const int*)d_in[3];
    const int* ei_rv = (const int*)d_in[4];
    const float* ea_rr = (const float*)d_in[5];
    const float* ea_vr = (const float*)d_in[6];
    const float* ea_rv = (const float*)d_in[7];
    const float* Wsrc1 = (const float*)d_in[8];
    const float* Wdst1 = (const float*)d_in[9];
    const float* asrc1 = (const float*)d_in[10];
    const float* adst1 = (const float*)d_in[11];
    const float* Wsrc2 = (const float*)d_in[13];
    const float* Wdst2 = (const float*)d_in[14];
    const float* asrc2 = (const float*)d_in[15];
    const float* adst2 = (const float*)d_in[16];
    const float* bn_gamma = (const float*)d_in[18];
    const float* bn_beta  = (const float*)d_in[19];
    const float* Wp   = (const float*)d_in[20];
    const float* bp   = (const float*)d_in[21];
    const float* Wlin = (const float*)d_in[22];
    const float* blin = (const float*)d_in[23];
    float* out = (float*)d_out;

    float* w = (float*)d_ws;
    size_t off = 0;
    float* scR   = w + off; off += (size_t)NR_ * 8;
    float* scV   = w + off; off += (size_t)NV_ * 4;
    float* s4    = w + off; off += 512;
    float* foldR = w + off; off += 2 * 128 * 8;
    float* foldV = w + off; off += 2 * 128 * 4;
    float* wp2   = w + off; off += 48;
    float* cterm = w + off; off += 8;
    float* fw    = w + off; off += 512;
    float* ssR   = w + off; off += (size_t)NR_ * 4;
    float* ssV   = w + off; off += (size_t)NV_ * 4;
    __bf16* o_r  = (__bf16*)(w + off); off += (size_t)NR_ * 128 / 2;
    __bf16* o_v  = (__bf16*)(w + off); off += (size_t)NV_ * 128 / 2;
    __bf16* hs_a = (__bf16*)(w + off); off += (size_t)NR_ * 128 / 2;
    __bf16* hs_b = (__bf16*)(w + off); off += (size_t)NV_ * 128 / 2;
    __bf16* hs_c = (__bf16*)(w + off); off += (size_t)NR_ * 128 / 2;
    __bf16* xrb  = (__bf16*)(w + off); off += (size_t)NR_ * 128 / 2;
    __bf16* xvb  = (__bf16*)(w + off); off += (size_t)NV_ * 128 / 2;
    __bf16* Wt   = (__bf16*)(w + off); off += 3 * 128 * 128 / 2;
    int* iw = (int*)(w + off);
    size_t ioff = 0;
    int* row  = iw + ioff; ioff += NTOT_ + 1;
    int* cnt  = iw + ioff; ioff += NTOT_;
    int* bsum = iw + ioff; ioff += SCAN_NB;
    int* rank = iw + ioff; ioff += ETOT_;
    int* cs   = iw + ioff; ioff += ETOT_;

    hipMemsetAsync(cnt, 0, NTOT_ * sizeof(int), stream);
    precompute_hist<<<PREB + HISTB, 256, 0, stream>>>(
        Wsrc1, Wdst1, asrc1, adst1, Wsrc2, Wdst2, asrc2, adst2,
        Wp, bp, Wlin, blin, ei_rr, ei_vr, ei_rv,
        foldR, foldV, wp2, cterm, fw, Wt, cnt, rank);

    scan_reduce<<<SCAN_NB, 256, 0, stream>>>(cnt, bsum);
    scan_write<<<SCAN_NB, 256, 0, stream>>>(cnt, bsum, row);
    scatter_all<<<HISTB, 256, 0, stream>>>(ei_rr, ei_vr, ei_rv, row, rank, cs);
    gemm_l1_all<<<2 * L1B_R + L1B_V, 256, 0, stream>>>(
        x_req, x_veh, Wsrc1, foldR, foldV, hs_a, hs_b, hs_c, scR, scV);

    for (int l = 0; l < 2; ++l) {
        if (l == 1) {
            gemm_mfma_all<<<2 * MFB_R + MFB_V, 256, 0, stream>>>(xrb, xvb, Wt, hs_a, hs_b, hs_c);
        }
        agg_all<<<AGB_R + AGB_V, 256, 0, stream>>>(row, cs, hs_a, hs_b, hs_c, scR, scV, o_r, o_v, s4);
        bn_stats_all<<<BN_BLKS_R + BN_BLKS_V, 256, 0, stream>>>(o_r, o_v, s4);
        if (l == 0) {
            bn_norm_fused<8, 4><<<BNN_R + BNN_V, 256, 0, stream>>>(
                o_r, o_v, s4, bn_gamma, bn_beta, xrb, xvb,
                foldR + 1024, foldV + 512, scR, scV);
        } else {
            bn_norm_fused<4, 4><<<BNN_R + BNN_V, 256, 0, stream>>>(
                o_r, o_v, s4, bn_gamma + 256, bn_beta + 256, xrb, xvb,
                fw, fw, ssR, ssV);
        }
    }

    final_edge_all<<<(ETOT_ + 255) / 256, 256, 0, stream>>>(ei_rr, ei_vr, ei_rv, ea_rr, ea_vr, ea_rv,
                                                            ssR, ssV, wp2, cterm, out);
}